// Round 7
// baseline (205.687 us; speedup 1.0000x reference)
//
#include <hip/hip_runtime.h>
#include <hip/hip_bf16.h>

// EPN layer: B=8, N=256, F=32, E_DIM=8, HID=32, IN_DIM=74, T=3
// Single persistent kernel, grid 512 (2 blocks/CU guaranteed co-resident:
// launch_bounds(256,2) -> VGPR<=256 -> >=2 blocks/CU; LDS 41KB -> >=3).
// Manual grid barrier (counter in ws, hipMemsetAsync-reset each call;
// release fence + device atomicAdd + acquire spin = grid.sync lowering).
// Each block owns 4 consecutive (b,i); j-side staging (base rows, q_j) is
// i-independent -> once per (t,block); e rows prefetched across pairs.
// Hot body = round-5-validated: transposed layer-1 MFMA
//   x1^T = mfma(A=[W1e;I;qrow], B=[e|baseJ|q_j] rows) + fp32 C = i-side,
//   register shuffle-exchange into layer-2 A-frags, fused b2/relu/W3/mn
//   epilogue, both dirs, no block barriers in the hot path (wave-local LDS).

typedef __attribute__((ext_vector_type(8))) short short8;
typedef __attribute__((ext_vector_type(4))) float f32x4;
union U4S8 { uint4 u; short8 s; };
#define F4(p) (*(const float4*)(p))

__device__ __forceinline__ unsigned pkbf2(float lo, float hi) {
    unsigned a = __bfloat16_as_ushort(__float2bfloat16(lo));
    unsigned b = __bfloat16_as_ushort(__float2bfloat16(hi));
    return a | (b << 16);
}
__device__ __forceinline__ float bf2f(unsigned short u) {
    return __uint_as_float(((unsigned)u) << 16);
}

__device__ __forceinline__ void gbar(unsigned* bar, unsigned target) {
    __syncthreads();                 // drains vmcnt: block's stores are in L2
    if (threadIdx.x == 0) {
        __threadfence();             // release: write back dirty L2 (agent scope)
        atomicAdd(bar, 1u);          // device-scope by default on gfx950
        while (__hip_atomic_load(bar, __ATOMIC_ACQUIRE,
                                 __HIP_MEMORY_SCOPE_AGENT) < target)
            __builtin_amdgcn_s_sleep(2);
        __threadfence();             // acquire: invalidate stale caches
    }
    __syncthreads();
}

__global__ __launch_bounds__(256, 2) void epn_fused(
    const float* __restrict__ h, const float* __restrict__ e,
    const float* __restrict__ q0, const float* __restrict__ mask,
    const float* __restrict__ W1, const float* __restrict__ b1,
    const float* __restrict__ W2, const float* __restrict__ b2,
    const float* __restrict__ W3,
    unsigned short* __restrict__ basePbf, unsigned short* __restrict__ baseQbf,
    unsigned* __restrict__ W2T, uint4* __restrict__ WA,
    float* __restrict__ qA, float* __restrict__ qB, float* __restrict__ qOut,
    unsigned* __restrict__ bar)
{
    __shared__ uint4 sxJ[8][256];   // j-side base rows: 0-3 baseQ, 4-7 baseP (32KB)
    __shared__ uint4 se[2][256];    // e rows bf16, double-buffered per pair (8KB)
    __shared__ float red[16];

    const int tid  = threadIdx.x, j = tid;
    const int lane = tid & 63, w = tid >> 6;
    const int l15  = lane & 15, sl = lane >> 4;
    const int bi0  = blockIdx.x * 4;      // 4 consecutive pairs, same b
    const int b    = bi0 >> 8;

    // ================= phase 0: q-independent prework =================
    for (int g = blockIdx.x * 256 + tid; g < 198528; g += 131072) {
        if (g < 196608) {
            int t = g >> 16, lg = g & 65535;
            const float* W1t = W1 + t*2368;
            int node = lg >> 5, k = lg & 31;
            const float* hn = h + node*32;
            float p = b1[t*32 + k], qq = 0.f;
            #pragma unroll
            for (int f = 0; f < 32; ++f) {
                float hv = hn[f];
                p  += hv * W1t[f*32 + k];
                qq += hv * W1t[(33+f)*32 + k];
            }
            basePbf[g] = __bfloat16_as_ushort(__float2bfloat16(p));
            baseQbf[g] = __bfloat16_as_ushort(__float2bfloat16(qq));
        } else if (g < 198144) {
            int gg = g - 196608;               // W2^T bf16-pair pack (r2)
            int t = gg >> 9, lg = gg & 511;
            int n = lg >> 4, kp = lg & 15;
            const float* W2t = W2 + t*1024;
            W2T[gg] = pkbf2(W2t[(2*kp)*32 + n], W2t[(2*kp+1)*32 + n]);
        } else {
            int gg = g - 198144;               // layer-1 A frags [W1e;I] (r4)
            int t = gg >> 7, g2 = gg & 127;
            int kt = g2 >> 6, ln = g2 & 63;
            int L15 = ln & 15, SL = ln >> 4;
            const float* W1t = W1 + t*2368;
            float v[8];
            #pragma unroll
            for (int p2 = 0; p2 < 8; ++p2) {
                int d = SL*8 + p2;
                v[p2] = (d < 8) ? W1t[(66+d)*32 + kt*16 + L15]
                                : ((kt*16 + L15 == d - 8) ? 1.0f : 0.0f);
            }
            WA[gg] = make_uint4(pkbf2(v[0],v[1]), pkbf2(v[2],v[3]),
                                pkbf2(v[4],v[5]), pkbf2(v[6],v[7]));
        }
    }

    // t-independent constants
    U4S8 wa1; wa1.u = make_uint4(0u,0u,0u,0u);   // kt1 chunk1 (I rows, r4)
    if (sl == 0 && l15 >= 8) {
        int p = l15 - 8;
        unsigned v = 0x3F80u << ((p & 1) * 16);
        wa1.u.x = ((p>>1)==0)?v:0u;  wa1.u.y = ((p>>1)==1)?v:0u;
        wa1.u.z = ((p>>1)==2)?v:0u;  wa1.u.w = ((p>>1)==3)?v:0u;
    }
    const int srcA = ((sl & 1) << 5) + l15, srcB = srcA + 16;
    const bool ktHi = (sl >= 2);
    float maskj = mask[b*256 + j];

    gbar(bar, 512u);

    // ================= t loop =================
    for (int t = 0; t < 3; ++t) {
        const float* qsrc = (t == 0) ? q0 : ((t == 1) ? qA : qB);
        float* qdst       = (t == 2) ? qOut : ((t == 0) ? qA : qB);
        const float* W1t   = W1 + t*2368;
        const float* qrowP = W1t + 32*32;
        const float* qrowQ = W1t + 65*32;
        const uint4* W2T4  = (const uint4*)(W2T + t*512);
        const uint4* WAt   = WA + t*128;
        const unsigned short* bP = basePbf + t*65536;
        const unsigned short* bQ = baseQbf + t*65536;
        const float* b2t = b2 + t*32;
        const float* W3t = W3 + t*32;

        // ---- per-t staging: j-side base rows (i-independent!) ----
        {
            const uint4* bq = ((const uint4*)bQ) + (size_t)(b*256 + j)*4;
            const uint4* bp = ((const uint4*)bP) + (size_t)(b*256 + j)*4;
            sxJ[0][j]=bq[0]; sxJ[1][j]=bq[1]; sxJ[2][j]=bq[2]; sxJ[3][j]=bq[3];
            sxJ[4][j]=bp[0]; sxJ[5][j]=bp[1]; sxJ[6][j]=bp[2]; sxJ[7][j]=bp[3];
        }
        float qjv = qsrc[b*256 + j];
        unsigned qpk = __bfloat16_as_ushort(__float2bfloat16(qjv));

        // ---- per-t hoisted fragments (r5 verbatim) ----
        U4S8 wa00, wa01;
        wa00.u = WAt[lane];
        wa01.u = WAt[64 + lane];
        unsigned aqQ0 = 0, aqQ1 = 0, aqP0 = 0, aqP1 = 0;
        if (sl == 0) {
            aqQ0 = __bfloat16_as_ushort(__float2bfloat16(qrowQ[l15]));
            aqQ1 = __bfloat16_as_ushort(__float2bfloat16(qrowQ[16 + l15]));
            aqP0 = __bfloat16_as_ushort(__float2bfloat16(qrowP[l15]));
            aqP1 = __bfloat16_as_ushort(__float2bfloat16(qrowP[16 + l15]));
        }
        U4S8 bu0, bu1;
        bu0.u = W2T4[l15*4 + sl];
        bu1.u = W2T4[(l15 + 16)*4 + sl];
        float b2v0 = b2t[l15], b2v1 = b2t[l15+16];
        float w3v0 = W3t[l15], w3v1 = W3t[l15+16];
        float qrP0v[4], qrP1v[4], qrQ0v[4], qrQ1v[4];
        #pragma unroll
        for (int r = 0; r < 4; ++r) {
            qrP0v[r] = qrowP[sl*4 + r];  qrP1v[r] = qrowP[16 + sl*4 + r];
            qrQ0v[r] = qrowQ[sl*4 + r];  qrQ1v[r] = qrowQ[16 + sl*4 + r];
        }

        // prefetch pair 0's e row
        const float* ep0 = e + ((size_t)bi0*256 + j)*8;
        float4 a0 = F4(ep0), a1 = F4(ep0 + 4);

        for (int p = 0; p < 4; ++p) {
            const int bi = bi0 + p;
            float4 e0 = a0, e1 = a1;
            if (p < 3) {   // prefetch next pair under this pair's compute
                const float* epn = e + ((size_t)(bi + 1)*256 + j)*8;
                a0 = F4(epn); a1 = F4(epn + 4);
            }
            float mx = fmaxf(fmaxf(fmaxf(e0.x,e0.y),fmaxf(e0.z,e0.w)),
                             fmaxf(fmaxf(e1.x,e1.y),fmaxf(e1.z,e1.w)));
            float nearf = (fminf(fmaxf(mx, 1e-8f), 1e5f) != 1e-8f) ? 1.f : 0.f;
            float mn = mask[bi] * maskj * nearf;     // 0.5 at the end
            const int par = p & 1;
            se[par][j] = make_uint4(pkbf2(e0.x,e0.y), pkbf2(e0.z,e0.w),
                                    pkbf2(e1.x,e1.y), pkbf2(e1.z,e1.w));
            const uint4* base_d0 = (sl == 0) ? &se[par][0] : &sxJ[sl-1][0];
            const uint4* base_d1 = (sl == 0) ? &se[par][0] : &sxJ[3+sl][0];

            // i-side C vectors (r5 verbatim)
            float qi = qsrc[bi];
            const unsigned short* bPi = bP + (size_t)bi*32;
            const unsigned short* bQi = bQ + (size_t)bi*32;
            ushort4 bp0 = *(const ushort4*)(bPi + sl*4);
            ushort4 bp1 = *(const ushort4*)(bPi + 16 + sl*4);
            ushort4 bq0 = *(const ushort4*)(bQi + sl*4);
            ushort4 bq1 = *(const ushort4*)(bQi + 16 + sl*4);
            f32x4 ckP0 = {bf2f(bp0.x)+qi*qrP0v[0], bf2f(bp0.y)+qi*qrP0v[1],
                          bf2f(bp0.z)+qi*qrP0v[2], bf2f(bp0.w)+qi*qrP0v[3]};
            f32x4 ckP1 = {bf2f(bp1.x)+qi*qrP1v[0], bf2f(bp1.y)+qi*qrP1v[1],
                          bf2f(bp1.z)+qi*qrP1v[2], bf2f(bp1.w)+qi*qrP1v[3]};
            f32x4 ckQ0 = {bf2f(bq0.x)+qi*qrQ0v[0], bf2f(bq0.y)+qi*qrQ0v[1],
                          bf2f(bq0.z)+qi*qrQ0v[2], bf2f(bq0.w)+qi*qrQ0v[3]};
            f32x4 ckQ1 = {bf2f(bq1.x)+qi*qrQ1v[0], bf2f(bq1.y)+qi*qrQ1v[1],
                          bf2f(bq1.z)+qi*qrQ1v[2], bf2f(bq1.w)+qi*qrQ1v[3]};

            float tot = 0.f;
            #pragma unroll
            for (int rt = 0; rt < 4; ++rt) {
                const int rl  = rt*16 + l15;
                const int row = w*64 + rl;
                unsigned qr = __shfl(qpk, rl);
                U4S8 bc2; bc2.u = make_uint4((sl == 0) ? (qr & 0xFFFFu) : 0u, 0u, 0u, 0u);
                float pA[4], pB[4];
                #pragma unroll
                for (int dir = 0; dir < 2; ++dir) {
                    U4S8 bc0, bc1, aq0, aq1;
                    bc0.u = dir ? base_d1[row] : base_d0[row];
                    bc1.u = dir ? sxJ[7][row]  : sxJ[3][row];
                    aq0.u = make_uint4(dir ? aqP0 : aqQ0, 0u, 0u, 0u);
                    aq1.u = make_uint4(dir ? aqP1 : aqQ1, 0u, 0u, 0u);
                    f32x4 c0 = dir ? ckQ0 : ckP0;
                    f32x4 c1 = dir ? ckQ1 : ckP1;
                    f32x4 dk0 = __builtin_amdgcn_mfma_f32_16x16x32_bf16(wa00.s, bc0.s, c0, 0,0,0);
                    dk0 = __builtin_amdgcn_mfma_f32_16x16x32_bf16(aq0.s, bc2.s, dk0, 0,0,0);
                    f32x4 dk1 = __builtin_amdgcn_mfma_f32_16x16x32_bf16(wa01.s, bc0.s, c1, 0,0,0);
                    dk1 = __builtin_amdgcn_mfma_f32_16x16x32_bf16(wa1.s,  bc1.s, dk1, 0,0,0);
                    dk1 = __builtin_amdgcn_mfma_f32_16x16x32_bf16(aq1.s,  bc2.s, dk1, 0,0,0);
                    unsigned pk00 = pkbf2(fmaxf(dk0[0],0.f), fmaxf(dk0[1],0.f));
                    unsigned pk01 = pkbf2(fmaxf(dk0[2],0.f), fmaxf(dk0[3],0.f));
                    unsigned pk10 = pkbf2(fmaxf(dk1[0],0.f), fmaxf(dk1[1],0.f));
                    unsigned pk11 = pkbf2(fmaxf(dk1[2],0.f), fmaxf(dk1[3],0.f));
                    unsigned sA0l = __shfl(pk00, srcA), sA0h = __shfl(pk10, srcA);
                    unsigned sA1l = __shfl(pk01, srcA), sA1h = __shfl(pk11, srcA);
                    unsigned sB0l = __shfl(pk00, srcB), sB0h = __shfl(pk10, srcB);
                    unsigned sB1l = __shfl(pk01, srcB), sB1h = __shfl(pk11, srcB);
                    U4S8 a;
                    a.u.x = ktHi ? sA0h : sA0l;
                    a.u.y = ktHi ? sA1h : sA1l;
                    a.u.z = ktHi ? sB0h : sB0l;
                    a.u.w = ktHi ? sB1h : sB1l;
                    f32x4 z = {0.f, 0.f, 0.f, 0.f};
                    f32x4 d0 = __builtin_amdgcn_mfma_f32_16x16x32_bf16(a.s, bu0.s, z, 0,0,0);
                    f32x4 d1 = __builtin_amdgcn_mfma_f32_16x16x32_bf16(a.s, bu1.s, z, 0,0,0);
                    float* pp = dir ? pB : pA;
                    pp[0] = fmaxf(d0[0]+b2v0,0.f)*w3v0 + fmaxf(d1[0]+b2v1,0.f)*w3v1;
                    pp[1] = fmaxf(d0[1]+b2v0,0.f)*w3v0 + fmaxf(d1[1]+b2v1,0.f)*w3v1;
                    pp[2] = fmaxf(d0[2]+b2v0,0.f)*w3v0 + fmaxf(d1[2]+b2v1,0.f)*w3v1;
                    pp[3] = fmaxf(d0[3]+b2v0,0.f)*w3v0 + fmaxf(d1[3]+b2v1,0.f)*w3v1;
                }
                const int jb = rt*16 + sl*4;
                float m0 = __shfl(mn, jb+0), m1 = __shfl(mn, jb+1);
                float m2 = __shfl(mn, jb+2), m3 = __shfl(mn, jb+3);
                tot += m0*(pA[0]-pB[0]) + m1*(pA[1]-pB[1])
                     + m2*(pA[2]-pB[2]) + m3*(pA[3]-pB[3]);
            }
            #pragma unroll
            for (int off = 32; off > 0; off >>= 1) tot += __shfl_down(tot, off);
            if (lane == 0) red[p*4 + w] = tot;
        }
        __syncthreads();
        if (tid < 4) {
            int bi = bi0 + tid;
            qdst[bi] = qsrc[bi] + 0.5f*(red[tid*4+0] + red[tid*4+1]
                                      + red[tid*4+2] + red[tid*4+3]);
        }
        if (t < 2) gbar(bar, 512u * (t + 2));
    }
}

extern "C" void kernel_launch(void* const* d_in, const int* in_sizes, int n_in,
                              void* d_out, int out_size, void* d_ws, size_t ws_size,
                              hipStream_t stream) {
    (void)in_sizes; (void)n_in; (void)out_size; (void)ws_size;
    const float* h    = (const float*)d_in[0];
    const float* e    = (const float*)d_in[1];
    const float* q    = (const float*)d_in[2];
    const float* mask = (const float*)d_in[3];
    const float* W1   = (const float*)d_in[4];
    const float* b1   = (const float*)d_in[5];
    const float* W2   = (const float*)d_in[6];
    const float* b2   = (const float*)d_in[7];
    const float* W3   = (const float*)d_in[8];

    char* ws = (char*)d_ws;
    unsigned short* basePbf = (unsigned short*)ws;            // 384KB
    unsigned short* baseQbf = (unsigned short*)(ws + 393216); // 384KB
    float*    qA   = (float*)(ws + 786432);                   // 8KB
    float*    qB   = (float*)(ws + 794624);                   // 8KB
    unsigned* W2T  = (unsigned*)(ws + 802816);                // 6KB
    uint4*    WA   = (uint4*)(ws + 808960);                   // 6KB
    unsigned* bar  = (unsigned*)(ws + 815104);                // 4B
    float*    qOut = (float*)d_out;

    hipMemsetAsync(bar, 0, sizeof(unsigned), stream);   // capture-legal
    epn_fused<<<512, 256, 0, stream>>>(h, e, q, mask, W1, b1, W2, b2, W3,
                                       basePbf, baseQbf, W2T, WA,
                                       qA, qB, qOut, bar);
}

// Round 9
// 52.754 us; speedup vs baseline: 3.8989x; 3.8989x over previous
//
#include <hip/hip_runtime.h>
#include <hip/hip_bf16.h>

// EPN layer: B=8, N=256, F=32, E_DIM=8, HID=32, IN_DIM=74, T=3
// Structure = round-5 (best: 58.1us): 1 pre + 3 main launches, grid 2048,
// one (b,i) per block, both dirs per block, no hot-path block barriers.
// Round-8/9 change: layer-2 uses mfma_f32_16x16x16 bf16 (K=16) whose
// A-fragment layout (m=l15, k=sl*4+r) EXACTLY matches layer-1's transposed
// output (x1^T: lane holds k=sl*4+r for j=l15) -> the 8-shfl register
// exchange per dir*rt (64 ds_bpermutes/pair, the r7-diagnosed latency
// bottleneck) is deleted. W2 prepacked into 4 K=16 B-frags. Mask factors
// move from 4 shfls/rt to one wave-local LDS float4 read.
// r9 fix: the 16x16x16 builtin exists on the DEVICE pass only
// (__builtin_amdgcn_mfma_f32_16x16x16bf16_1k); HIP's host pass also parses
// __global__ bodies, so gate on __HIP_DEVICE_COMPILE__ with a host stub.

typedef __attribute__((ext_vector_type(8))) short short8;
typedef __attribute__((ext_vector_type(4))) short short4v;
typedef __attribute__((ext_vector_type(4))) float f32x4;
union U4S8 { uint4 u; short8 s; };
union U2S4 { uint2 u; short4v s; };
#define F4(p) (*(const float4*)(p))

#if defined(__HIP_DEVICE_COMPILE__)
# if __has_builtin(__builtin_amdgcn_mfma_f32_16x16x16bf16_1k)
#  define MFMA16(a,b,c) __builtin_amdgcn_mfma_f32_16x16x16bf16_1k(a,b,c,0,0,0)
# elif __has_builtin(__builtin_amdgcn_mfma_f32_16x16x16_bf16)
#  define MFMA16(a,b,c) __builtin_amdgcn_mfma_f32_16x16x16_bf16(a,b,c,0,0,0)
# else
#  error "no 16x16x16 bf16 MFMA builtin on this target"
# endif
#else
// host pass parses but never executes device bodies
# define MFMA16(a,b,c) (f32x4{0.f,0.f,0.f,0.f})
#endif

__device__ __forceinline__ unsigned pkbf2(float lo, float hi) {
    unsigned a = __bfloat16_as_ushort(__float2bfloat16(lo));
    unsigned b = __bfloat16_as_ushort(__float2bfloat16(hi));
    return a | (b << 16);
}
__device__ __forceinline__ float bf2f(unsigned short u) {
    return __uint_as_float(((unsigned)u) << 16);
}

// ---- pre: bases for all 3 t + W2 K=16 B-frags + layer-1 A-frags ----
__global__ __launch_bounds__(256) void epn_pre(
    const float* __restrict__ h, const float* __restrict__ W1,
    const float* __restrict__ b1, const float* __restrict__ W2,
    unsigned short* __restrict__ basePbf, unsigned short* __restrict__ baseQbf,
    uint2* __restrict__ W2T16, uint4* __restrict__ WA)
{
    const int t  = blockIdx.x >> 8;
    const int lg = (blockIdx.x & 255) * 256 + threadIdx.x;  // 0..65535
    const float* W1t = W1 + t*2368;
    if (lg < 256) {
        // W2 as four 16x16x16 B-frags: f = kh*2+nt; lane (sl,l15):
        //   reg r holds B[k = kh*16+sl*4+r][n = nt*16+l15]
        int f = lg >> 6, lane = lg & 63;
        int kh = f >> 1, nt = f & 1;
        int sl = lane >> 4, l15 = lane & 15;
        int k0 = kh*16 + sl*4, n = nt*16 + l15;
        const float* W2t = W2 + t*1024;
        W2T16[t*256 + lg] = make_uint2(
            pkbf2(W2t[k0*32 + n],     W2t[(k0+1)*32 + n]),
            pkbf2(W2t[(k0+2)*32 + n], W2t[(k0+3)*32 + n]));
    } else if (lg < 384) {
        // layer-1 A frags [W1e;I], K-chunk0, kt = 0/1 (validated r4/r5)
        int g2 = lg - 256;
        int kt = g2 >> 6, lane = g2 & 63;
        int l15 = lane & 15, sl = lane >> 4;
        float v[8];
        #pragma unroll
        for (int p = 0; p < 8; ++p) {
            int d = sl*8 + p;
            v[p] = (d < 8) ? W1t[(66+d)*32 + kt*16 + l15]
                           : ((kt*16 + l15 == d - 8) ? 1.0f : 0.0f);
        }
        WA[t*128 + g2] = make_uint4(pkbf2(v[0],v[1]), pkbf2(v[2],v[3]),
                                    pkbf2(v[4],v[5]), pkbf2(v[6],v[7]));
    }
    const int node = lg >> 5, k = lg & 31;
    const float* hn = h + node*32;
    float p = b1[t*32 + k], qq = 0.f;
    #pragma unroll
    for (int f = 0; f < 32; ++f) {
        float hv = hn[f];
        p  += hv * W1t[f*32 + k];
        qq += hv * W1t[(33+f)*32 + k];
    }
    basePbf[t*65536 + lg] = __bfloat16_as_ushort(__float2bfloat16(p));
    baseQbf[t*65536 + lg] = __bfloat16_as_ushort(__float2bfloat16(qq));
}

// ---- main: one block per (b,i), both dirs; writes q_dst[bi] ----
__global__ __launch_bounds__(256, 4) void epn_main(
    const float* __restrict__ e, const float* __restrict__ mask,
    const uint4* __restrict__ bP4, const uint4* __restrict__ bQ4,
    const float* __restrict__ qrowP, const float* __restrict__ qrowQ,
    const uint2* __restrict__ W2T16, const uint4* __restrict__ WA,
    const float* __restrict__ b2, const float* __restrict__ W3,
    const float* __restrict__ q_src, float* __restrict__ q_dst)
{
    __shared__ uint4 sx[9][256];   // SoA: slot0=e, 1-4=baseQ, 5-8=baseP (36.9KB)
    __shared__ float mnL[256];
    __shared__ float red[4];

    const int bi = blockIdx.x, b = bi >> 8;
    const int tid = threadIdx.x, j = tid;
    const int lane = tid & 63, w = tid >> 6;
    const int l15 = lane & 15, sl = lane >> 4;

    // ---------- staging (all wave-local consumption; no barrier) ----------
    float qj = q_src[b*256 + j];
    unsigned qpk = __bfloat16_as_ushort(__float2bfloat16(qj));
    const float* ejp = e + ((size_t)bi*256 + j)*8;
    float4 e0 = F4(ejp), e1 = F4(ejp + 4);
    float mx = fmaxf(fmaxf(fmaxf(e0.x,e0.y),fmaxf(e0.z,e0.w)),
                     fmaxf(fmaxf(e1.x,e1.y),fmaxf(e1.z,e1.w)));
    float nearf = (fminf(fmaxf(mx, 1e-8f), 1e5f) != 1e-8f) ? 1.f : 0.f;
    mnL[j] = mask[bi] * mask[b*256 + j] * nearf;   // 0.5 applied at the end
    sx[0][j] = make_uint4(pkbf2(e0.x,e0.y), pkbf2(e0.z,e0.w),
                          pkbf2(e1.x,e1.y), pkbf2(e1.z,e1.w));
    {
        const uint4* bq = bQ4 + (size_t)(b*256 + j)*4;
        const uint4* bp = bP4 + (size_t)(b*256 + j)*4;
        sx[1][j]=bq[0]; sx[2][j]=bq[1]; sx[3][j]=bq[2]; sx[4][j]=bq[3];
        sx[5][j]=bp[0]; sx[6][j]=bp[1]; sx[7][j]=bp[2]; sx[8][j]=bp[3];
    }

    // ---------- hoisted fragments ----------
    U4S8 wa00, wa01, wa1;
    wa00.u = WA[lane];
    wa01.u = WA[64 + lane];
    wa1.u  = make_uint4(0u,0u,0u,0u);   // kt1 chunk1 (I rows for J[24:32], r4)
    if (sl == 0 && l15 >= 8) {
        int p = l15 - 8;
        unsigned v = 0x3F80u << ((p & 1) * 16);
        wa1.u.x = ((p>>1)==0)?v:0u;  wa1.u.y = ((p>>1)==1)?v:0u;
        wa1.u.z = ((p>>1)==2)?v:0u;  wa1.u.w = ((p>>1)==3)?v:0u;
    }
    unsigned aqQ0 = 0, aqQ1 = 0, aqP0 = 0, aqP1 = 0;
    if (sl == 0) {
        aqQ0 = __bfloat16_as_ushort(__float2bfloat16(qrowQ[l15]));
        aqQ1 = __bfloat16_as_ushort(__float2bfloat16(qrowQ[16 + l15]));
        aqP0 = __bfloat16_as_ushort(__float2bfloat16(qrowP[l15]));
        aqP1 = __bfloat16_as_ushort(__float2bfloat16(qrowP[16 + l15]));
    }
    float qi = q_src[bi];
    const unsigned short* bPi = (const unsigned short*)bP4 + (size_t)bi*32;
    const unsigned short* bQi = (const unsigned short*)bQ4 + (size_t)bi*32;
    f32x4 ckP0, ckP1, ckQ0, ckQ1;
    #pragma unroll
    for (int r = 0; r < 4; ++r) {
        int k0 = sl*4 + r, k1 = 16 + sl*4 + r;
        ckP0[r] = bf2f(bPi[k0]) + qi * qrowP[k0];
        ckP1[r] = bf2f(bPi[k1]) + qi * qrowP[k1];
        ckQ0[r] = bf2f(bQi[k0]) + qi * qrowQ[k0];
        ckQ1[r] = bf2f(bQi[k1]) + qi * qrowQ[k1];
    }
    // layer-2 B-frags (K=16): f = kh*2+nt
    U2S4 bu00, bu10, bu01, bu11;
    bu00.u = W2T16[0*64 + lane];   // k-half 0, n 0..15
    bu01.u = W2T16[1*64 + lane];   // k-half 0, n 16..31
    bu10.u = W2T16[2*64 + lane];   // k-half 1, n 0..15
    bu11.u = W2T16[3*64 + lane];   // k-half 1, n 16..31
    float b2v0 = b2[l15], b2v1 = b2[l15+16];
    float w3v0 = W3[l15], w3v1 = W3[l15+16];
    const int slot0_d0 = (sl == 0) ? 0 : sl;        // dir0 chunk0: [e|baseQ]
    const int slot0_d1 = (sl == 0) ? 0 : 4 + sl;    // dir1 chunk0: [e|baseP]

    float tot = 0.f;
    #pragma unroll
    for (int rt = 0; rt < 4; ++rt) {
        const int rl  = rt*16 + l15;
        const int row = w*64 + rl;
        unsigned qr = __shfl(qpk, rl);
        U4S8 bc2; bc2.u = make_uint4((sl == 0) ? (qr & 0xFFFFu) : 0u, 0u, 0u, 0u);
        float pA[4], pB[4];
        #pragma unroll
        for (int dir = 0; dir < 2; ++dir) {
            U4S8 bc0, bc1, aq0, aq1;
            bc0.u = sx[dir ? slot0_d1 : slot0_d0][row];
            bc1.u = sx[dir ? 8 : 4][row];
            aq0.u = make_uint4(dir ? aqP0 : aqQ0, 0u, 0u, 0u);
            aq1.u = make_uint4(dir ? aqP1 : aqQ1, 0u, 0u, 0u);
            f32x4 c0 = dir ? ckQ0 : ckP0;
            f32x4 c1 = dir ? ckQ1 : ckP1;
            // layer-1 (transposed, r5-validated): lane -> x1[j=l15][k=sl*4+r (+16)]
            f32x4 dk0 = __builtin_amdgcn_mfma_f32_16x16x32_bf16(wa00.s, bc0.s, c0, 0,0,0);
            dk0 = __builtin_amdgcn_mfma_f32_16x16x32_bf16(aq0.s, bc2.s, dk0, 0,0,0);
            f32x4 dk1 = __builtin_amdgcn_mfma_f32_16x16x32_bf16(wa01.s, bc0.s, c1, 0,0,0);
            dk1 = __builtin_amdgcn_mfma_f32_16x16x32_bf16(wa1.s,  bc1.s, dk1, 0,0,0);
            dk1 = __builtin_amdgcn_mfma_f32_16x16x32_bf16(aq1.s,  bc2.s, dk1, 0,0,0);
            // relu+pack: a0/a1 ARE K=16 A-frags (m=l15=j, k=sl*4+r) -> no exchange
            U2S4 a0, a1;
            a0.u = make_uint2(pkbf2(fmaxf(dk0[0],0.f), fmaxf(dk0[1],0.f)),
                              pkbf2(fmaxf(dk0[2],0.f), fmaxf(dk0[3],0.f)));
            a1.u = make_uint2(pkbf2(fmaxf(dk1[0],0.f), fmaxf(dk1[1],0.f)),
                              pkbf2(fmaxf(dk1[2],0.f), fmaxf(dk1[3],0.f)));
            // layer-2: two K=16 accumulating MFMAs per n-half
            f32x4 z = {0.f, 0.f, 0.f, 0.f};
            f32x4 d0 = MFMA16(a0.s, bu00.s, z);
            d0 = MFMA16(a1.s, bu10.s, d0);
            f32x4 d1 = MFMA16(a0.s, bu01.s, z);
            d1 = MFMA16(a1.s, bu11.s, d1);
            // fused b2/relu/W3 epilogue: d[r] = y[j = rt*16+sl*4+r][n-half]
            float* pp = dir ? pB : pA;
            pp[0] = fmaxf(d0[0]+b2v0,0.f)*w3v0 + fmaxf(d1[0]+b2v1,0.f)*w3v1;
            pp[1] = fmaxf(d0[1]+b2v0,0.f)*w3v0 + fmaxf(d1[1]+b2v1,0.f)*w3v1;
            pp[2] = fmaxf(d0[2]+b2v0,0.f)*w3v0 + fmaxf(d1[2]+b2v1,0.f)*w3v1;
            pp[3] = fmaxf(d0[3]+b2v0,0.f)*w3v0 + fmaxf(d1[3]+b2v1,0.f)*w3v1;
        }
        // mask factors: wave-local LDS float4 (replaces 4 shfls)
        float4 mr = *(const float4*)&mnL[w*64 + rt*16 + sl*4];
        tot += mr.x*(pA[0]-pB[0]) + mr.y*(pA[1]-pB[1])
             + mr.z*(pA[2]-pB[2]) + mr.w*(pA[3]-pB[3]);
    }
    #pragma unroll
    for (int off = 32; off > 0; off >>= 1) tot += __shfl_down(tot, off);
    if (lane == 0) red[w] = tot;
    __syncthreads();
    if (tid == 0)
        q_dst[bi] = q_src[bi] + 0.5f * (red[0] + red[1] + red[2] + red[3]);
}

extern "C" void kernel_launch(void* const* d_in, const int* in_sizes, int n_in,
                              void* d_out, int out_size, void* d_ws, size_t ws_size,
                              hipStream_t stream) {
    (void)in_sizes; (void)n_in; (void)out_size; (void)ws_size;
    const float* h    = (const float*)d_in[0];
    const float* e    = (const float*)d_in[1];
    const float* q    = (const float*)d_in[2];
    const float* mask = (const float*)d_in[3];
    const float* W1   = (const float*)d_in[4];
    const float* b1   = (const float*)d_in[5];
    const float* W2   = (const float*)d_in[6];
    const float* b2   = (const float*)d_in[7];
    const float* W3   = (const float*)d_in[8];

    char* ws = (char*)d_ws;
    unsigned short* basePbf = (unsigned short*)ws;            // 384KB
    unsigned short* baseQbf = (unsigned short*)(ws + 393216); // 384KB
    float* qA   = (float*)(ws + 786432);                      // 8KB
    float* qB   = (float*)(ws + 794624);                      // 8KB
    uint2* W2T16 = (uint2*)(ws + 802816);                     // 6KB
    uint4* WA    = (uint4*)(ws + 808960);                     // 6KB

    epn_pre<<<768, 256, 0, stream>>>(h, W1, b1, W2, basePbf, baseQbf, W2T16, WA);

    const float* qsrc = q;
    for (int t = 0; t < 3; ++t) {
        float* qdst = (t == 2) ? (float*)d_out : (t == 0 ? qA : qB);
        epn_main<<<2048, 256, 0, stream>>>(
            e, mask,
            (const uint4*)(basePbf + t*65536), (const uint4*)(baseQbf + t*65536),
            W1 + t*2368 + 32*32, W1 + t*2368 + 65*32,
            W2T16 + t*256, WA + t*128,
            b2 + t*32, W3 + t*32, qsrc, qdst);
        qsrc = qdst;
    }
}